// Round 4
// baseline (306.736 us; speedup 1.0000x reference)
//
#include <hip/hip_runtime.h>
#include <hip/hip_bf16.h>

#define BATCH 8
#define CIN   128
#define HH    256
#define WW    256
#define OUTC  64
#define INCH  1152   // CIN*9
#define HW    (HH*WW)

typedef __attribute__((ext_vector_type(8))) short short8;
typedef __attribute__((ext_vector_type(4))) float f32x4;

__device__ __forceinline__ unsigned short bf16r(float f) {
    unsigned u = __builtin_bit_cast(unsigned, f);
    u += 0x7fffu + ((u >> 16) & 1u);
    return (unsigned short)(u >> 16);
}

// wmod[b][tap][o][c] = bf16(weight[o][c*9+tap] * style[b][c*9+tap])
__global__ void __launch_bounds__(256) wmod_kernel(const float* __restrict__ weight,
                                                   const float* __restrict__ style,
                                                   unsigned short* __restrict__ wmod) {
    int i = blockIdx.x * 256 + threadIdx.x;
    if (i >= BATCH * 9 * OUTC * CIN) return;
    int c    = i & (CIN - 1);
    int rest = i >> 7;
    int o    = rest & (OUTC - 1);
    int bt   = rest >> 6;          // b*9 + tap
    int tap  = bt % 9;
    int b    = bt / 9;
    int k    = c * 9 + tap;
    float v = weight[o * INCH + k] * style[b * INCH + k];
    wmod[i] = bf16r(v);
}

// Block: 64 outputs x (8 rows x 32 cols) pixels. 4 waves, each 64 o x 64 px.
// Channel chunk = 32 (full MFMA K). LDS per buffer: paired pixel-rows, 128B:
//   addr(s,c) = (s>>1)*64 + ((((s&1)<<2)|(c>>3)) ^ ((s>>1)&7))*8 + (c&7)
// 2-phase pipeline: stage chunk k+1 into buf^1 while computing chunk k from
// buf -> global-load latency hides under MFMA; ONE barrier per chunk.
template <bool GW>
__global__ void __launch_bounds__(256, 3) conv_kernel(
    const float* __restrict__ x,
    const unsigned short* __restrict__ wmod,
    const float* __restrict__ weight,
    const float* __restrict__ style,
    float* __restrict__ out)
{
    __shared__ __align__(16) unsigned short xs_sm[2][170 * 64];

    const int tid = threadIdx.x;
    const int bx  = blockIdx.x;            // 0..255 spatial tile
    const int b   = blockIdx.y;            // batch
    const int h0  = (bx >> 3) * 8;
    const int w0  = (bx & 7) * 32;

    const int wv  = tid >> 6;
    const int l15 = tid & 15;
    const int kg  = (tid >> 4) & 3;

    // ---- staging geometry, hoisted: tasks t = tid + 256k, t < 1360
    int soff[6], slds[6];
    unsigned sok = 0;
#pragma unroll
    for (int k = 0; k < 6; ++k) {
        int t  = tid + k * 256;
        int tt = (t < 1360) ? t : 0;
        int cg  = tt / 340;
        int s   = tt - cg * 340;
        int r   = s / 34;
        int col = s - r * 34;
        int h = h0 - 1 + r, w = w0 - 1 + col;
        if (((unsigned)h < HH) && ((unsigned)w < WW)) sok |= (1u << k);
        soff[k] = cg * 8 * HW + h * WW + w;
        int q = s >> 1;
        int g = (((s & 1) << 2) | cg) ^ (q & 7);
        slds[k] = q * 64 + g * 8;
    }

    int prow[4], pcol[4];
#pragma unroll
    for (int ni = 0; ni < 4; ++ni) {
        int p = wv * 64 + ni * 16 + l15;
        prow[ni] = p >> 5;
        pcol[ni] = p & 31;
    }

    f32x4 acc[4][4];
#pragma unroll
    for (int mi = 0; mi < 4; ++mi)
#pragma unroll
        for (int ni = 0; ni < 4; ++ni) acc[mi][ni] = (f32x4){0.f, 0.f, 0.f, 0.f};

    auto stage = [&](int chunk, unsigned short* xsb) {
        const float* xb = x + ((size_t)(b * CIN + chunk * 32)) * HW;
#pragma unroll
        for (int k = 0; k < 6; ++k) {
            if (k < 5 || tid < 80) {
                bool ok = (sok >> k) & 1u;
                const float* xp = xb + soff[k];
                short8 sv;
#pragma unroll
                for (int j = 0; j < 8; ++j) {
                    float f = ok ? xp[(size_t)j * HW] : 0.f;
                    sv[j] = (short)bf16r(f);
                }
                *(short8*)&xsb[slds[k]] = sv;
            }
        }
    };

    auto compute = [&](int chunk, const unsigned short* xs) {
        const unsigned short* wmb =
            wmod + ((size_t)(b * 9) * OUTC) * CIN + chunk * 32;
#pragma unroll
        for (int tap = 0; tap < 9; ++tap) {
            const int kh = tap / 3, kw = tap % 3;

            short8 A[4];
            if (GW) {
                const unsigned short* wt = wmb + (size_t)tap * OUTC * CIN;
#pragma unroll
                for (int mi = 0; mi < 4; ++mi)
                    A[mi] = *(const short8*)(wt + (mi * 16 + l15) * CIN + kg * 8);
            } else {
#pragma unroll
                for (int mi = 0; mi < 4; ++mi) {
                    int o = mi * 16 + l15;
#pragma unroll
                    for (int j = 0; j < 8; ++j) {
                        int c = chunk * 32 + kg * 8 + j;
                        int k = c * 9 + tap;
                        A[mi][j] = (short)bf16r(weight[o * INCH + k] *
                                                style[b * INCH + k]);
                    }
                }
            }

            short8 Bv[4];
#pragma unroll
            for (int ni = 0; ni < 4; ++ni) {
                int s = (prow[ni] + kh) * 34 + pcol[ni] + kw;
                int q = s >> 1;
                int g = (((s & 1) << 2) | kg) ^ (q & 7);
                Bv[ni] = *(const short8*)&xs[q * 64 + g * 8];
            }
#pragma unroll
            for (int mi = 0; mi < 4; ++mi)
#pragma unroll
                for (int ni = 0; ni < 4; ++ni)
                    acc[mi][ni] = __builtin_amdgcn_mfma_f32_16x16x32_bf16(
                        A[mi], Bv[ni], acc[mi][ni], 0, 0, 0);
        }
    };

    // ---- 2-phase pipeline, static buffer indices
    stage(0, xs_sm[0]);
    __syncthreads();

    stage(1, xs_sm[1]);          // in flight during compute(0)
    compute(0, xs_sm[0]);
    __syncthreads();

    stage(2, xs_sm[0]);
    compute(1, xs_sm[1]);
    __syncthreads();

    stage(3, xs_sm[1]);
    compute(2, xs_sm[0]);
    __syncthreads();

    compute(3, xs_sm[1]);

    // ---- epilogue: D mapping col=lane&15 (pixel), row=(lane>>4)*4+r (o)
    float* op = out + ((size_t)b * OUTC) * HW;
#pragma unroll
    for (int mi = 0; mi < 4; ++mi) {
#pragma unroll
        for (int ni = 0; ni < 4; ++ni) {
            int p = wv * 64 + ni * 16 + l15;
            int h = h0 + (p >> 5), w = w0 + (p & 31);
#pragma unroll
            for (int r = 0; r < 4; ++r) {
                int o = mi * 16 + kg * 4 + r;
                op[(size_t)o * HW + h * WW + w] = acc[mi][ni][r];
            }
        }
    }
}

extern "C" void kernel_launch(void* const* d_in, const int* in_sizes, int n_in,
                              void* d_out, int out_size, void* d_ws, size_t ws_size,
                              hipStream_t stream) {
    const float* x      = (const float*)d_in[0];
    const float* style  = (const float*)d_in[1];
    const float* weight = (const float*)d_in[2];
    float* out = (float*)d_out;

    const size_t wmod_bytes = (size_t)BATCH * 9 * OUTC * CIN * sizeof(unsigned short);
    if (ws_size >= wmod_bytes) {
        int total = BATCH * 9 * OUTC * CIN;
        wmod_kernel<<<(total + 255) / 256, 256, 0, stream>>>(weight, style,
                                                             (unsigned short*)d_ws);
        conv_kernel<true><<<dim3(256, BATCH), 256, 0, stream>>>(
            x, (const unsigned short*)d_ws, nullptr, nullptr, out);
    } else {
        conv_kernel<false><<<dim3(256, BATCH), 256, 0, stream>>>(
            x, nullptr, weight, style, out);
    }
}

// Round 5
// 305.492 us; speedup vs baseline: 1.0041x; 1.0041x over previous
//
#include <hip/hip_runtime.h>
#include <hip/hip_bf16.h>

#define BATCH 8
#define CIN   128
#define HH    256
#define WW    256
#define OUTC  64
#define INCH  1152   // CIN*9
#define HW    (HH*WW)

typedef __attribute__((ext_vector_type(8))) short short8;
typedef __attribute__((ext_vector_type(4))) float f32x4;

__device__ __forceinline__ unsigned short bf16r(float f) {
    unsigned u = __builtin_bit_cast(unsigned, f);
    u += 0x7fffu + ((u >> 16) & 1u);
    return (unsigned short)(u >> 16);
}

// wmod[b][tap][o][c] = bf16(weight[o][c*9+tap] * style[b][c*9+tap])
__global__ void __launch_bounds__(256) wmod_kernel(const float* __restrict__ weight,
                                                   const float* __restrict__ style,
                                                   unsigned short* __restrict__ wmod) {
    int i = blockIdx.x * 256 + threadIdx.x;
    if (i >= BATCH * 9 * OUTC * CIN) return;
    int c    = i & (CIN - 1);
    int rest = i >> 7;
    int o    = rest & (OUTC - 1);
    int bt   = rest >> 6;          // b*9 + tap
    int tap  = bt % 9;
    int b    = bt / 9;
    int k    = c * 9 + tap;
    float v = weight[o * INCH + k] * style[b * INCH + k];
    wmod[i] = bf16r(v);
}

// Block: 64 outputs x (8 rows x 32 cols) pixels. 4 waves, each 64 o x 64 px.
// Chunk = 32 channels (one MFMA K). LDS buffer: paired pixel-rows, 128B/row:
//   addr(s,c) = (s>>1)*64 + ((((s&1)<<2)|(c>>3)) ^ ((s>>1)&7))*8 + (c&7)
// Pipeline per chunk (T14 split, bounded live state):
//   [issue G0] taps0-2 | write G0, issue G1 | taps3-5 | write G1, issue G2 |
//   taps6-8 | write G2 | barrier  -- each G = 2 tasks = 16 floats in flight.
// A-fragments ping-pong 2-deep. sched_barrier(0) fences bound reg pressure.
template <bool GW>
__global__ void __launch_bounds__(256, 3) conv_kernel(
    const float* __restrict__ x,
    const unsigned short* __restrict__ wmod,
    const float* __restrict__ weight,
    const float* __restrict__ style,
    float* __restrict__ out)
{
    __shared__ __align__(16) unsigned short xs_sm[2][170 * 64];

    const int tid = threadIdx.x;
    const int bx  = blockIdx.x;            // 0..255 spatial tile
    const int b   = blockIdx.y;            // batch
    const int h0  = (bx >> 3) * 8;
    const int w0  = (bx & 7) * 32;

    const int wv  = tid >> 6;
    const int l15 = tid & 15;
    const int kg  = (tid >> 4) & 3;

    // ---- staging geometry, hoisted: tasks t = tid + 256k, t < 1360
    int soff[6], slds[6];
    unsigned sok = 0;
#pragma unroll
    for (int k = 0; k < 6; ++k) {
        int t  = tid + k * 256;
        bool pred = (t < 1360);
        int tt = pred ? t : 0;
        int cg  = tt / 340;
        int s   = tt - cg * 340;
        int r   = s / 34;
        int col = s - r * 34;
        int h = h0 - 1 + r, w = w0 - 1 + col;
        if (pred && ((unsigned)h < HH) && ((unsigned)w < WW)) sok |= (1u << k);
        soff[k] = cg * 8 * HW + h * WW + w;
        int q = s >> 1;
        int g = (((s & 1) << 2) | cg) ^ (q & 7);
        slds[k] = q * 64 + g * 8;
    }

    int sbase[4];
#pragma unroll
    for (int ni = 0; ni < 4; ++ni) {
        int p = wv * 64 + ni * 16 + l15;
        sbase[ni] = (p >> 5) * 34 + (p & 31);
    }

    const float* xb_base = x + (size_t)b * CIN * HW;
    const unsigned short* wm_base = wmod + ((size_t)(b * 9) * OUTC) * CIN;

    short8 Areg[2][4];

    auto issueA = [&](int chunk, int tap, int slot) {
        if (GW) {
            const unsigned short* wt =
                wm_base + ((size_t)tap * OUTC) * CIN + chunk * 32;
#pragma unroll
            for (int mi = 0; mi < 4; ++mi)
                Areg[slot][mi] =
                    *(const short8*)(wt + (mi * 16 + l15) * CIN + kg * 8);
        } else {
#pragma unroll
            for (int mi = 0; mi < 4; ++mi) {
                int o = mi * 16 + l15;
#pragma unroll
                for (int j = 0; j < 8; ++j) {
                    int c = chunk * 32 + kg * 8 + j;
                    int k = c * 9 + tap;
                    Areg[slot][mi][j] =
                        (short)bf16r(weight[o * INCH + k] * style[b * INCH + k]);
                }
            }
        }
    };

    auto issueG = [&](int chunk, int grp, float (*gv)[8]) {
        const float* xb = xb_base + (size_t)(chunk * 32) * HW;
#pragma unroll
        for (int u = 0; u < 2; ++u) {
            int k = grp * 2 + u;
            bool ok = ((sok >> k) & 1u) && (k < 5 || tid < 80);
            const float* xp = xb + soff[k];
#pragma unroll
            for (int j = 0; j < 8; ++j)
                gv[u][j] = ok ? xp[(size_t)j * HW] : 0.0f;
        }
    };

    auto writeG = [&](int grp, float (*gv)[8], unsigned short* sbuf) {
#pragma unroll
        for (int u = 0; u < 2; ++u) {
            int k = grp * 2 + u;
            if (k < 5 || tid < 80) {
                short8 sv;
#pragma unroll
                for (int j = 0; j < 8; ++j) sv[j] = (short)bf16r(gv[u][j]);
                *(short8*)&sbuf[slds[k]] = sv;
            }
        }
    };

    f32x4 acc[4][4];

    auto do_chunk = [&](int chunk, const unsigned short* cbuf,
                        unsigned short* sbuf, bool do_stage) {
        float gv[2][8];
        issueA(chunk, 0, 0);
        if (do_stage) issueG(chunk + 1, 0, gv);
#pragma unroll
        for (int tg = 0; tg < 3; ++tg) {
#pragma unroll
            for (int tt = 0; tt < 3; ++tt) {
                const int tap = tg * 3 + tt;
                if (tap < 8) issueA(chunk, tap + 1, (tap + 1) & 1);
                const int kh = tap / 3, kw = tap % 3;
                short8 Bv[4];
#pragma unroll
                for (int ni = 0; ni < 4; ++ni) {
                    int s = sbase[ni] + kh * 34 + kw;
                    int q = s >> 1;
                    int g = (((s & 1) << 2) | kg) ^ (q & 7);
                    Bv[ni] = *(const short8*)&cbuf[q * 64 + g * 8];
                }
#pragma unroll
                for (int mi = 0; mi < 4; ++mi)
#pragma unroll
                    for (int ni = 0; ni < 4; ++ni)
                        acc[mi][ni] = __builtin_amdgcn_mfma_f32_16x16x32_bf16(
                            Areg[tap & 1][mi], Bv[ni], acc[mi][ni], 0, 0, 0);
            }
            __builtin_amdgcn_sched_barrier(0);
            if (do_stage) {
                writeG(tg, gv, sbuf);
                if (tg < 2) issueG(chunk + 1, tg + 1, gv);
            }
            __builtin_amdgcn_sched_barrier(0);
        }
    };

    // ---- prologue: stage chunk 0
    {
        float g0[2][8], g1[2][8], g2[2][8];
        issueG(0, 0, g0);
        issueG(0, 1, g1);
        issueG(0, 2, g2);
        writeG(0, g0, xs_sm[0]);
        writeG(1, g1, xs_sm[0]);
        writeG(2, g2, xs_sm[0]);
    }
#pragma unroll
    for (int mi = 0; mi < 4; ++mi)
#pragma unroll
        for (int ni = 0; ni < 4; ++ni) acc[mi][ni] = (f32x4){0.f, 0.f, 0.f, 0.f};
    __syncthreads();

    do_chunk(0, xs_sm[0], xs_sm[1], true);
    __syncthreads();
    do_chunk(1, xs_sm[1], xs_sm[0], true);
    __syncthreads();
    do_chunk(2, xs_sm[0], xs_sm[1], true);
    __syncthreads();
    do_chunk(3, xs_sm[1], nullptr, false);

    // ---- epilogue: D mapping col=lane&15 (pixel), row=(lane>>4)*4+r (o)
    float* op = out + ((size_t)b * OUTC) * HW;
#pragma unroll
    for (int mi = 0; mi < 4; ++mi) {
#pragma unroll
        for (int ni = 0; ni < 4; ++ni) {
            int p = wv * 64 + ni * 16 + l15;
            int h = h0 + (p >> 5), w = w0 + (p & 31);
#pragma unroll
            for (int r = 0; r < 4; ++r) {
                int o = mi * 16 + kg * 4 + r;
                op[(size_t)o * HW + h * WW + w] = acc[mi][ni][r];
            }
        }
    }
}

extern "C" void kernel_launch(void* const* d_in, const int* in_sizes, int n_in,
                              void* d_out, int out_size, void* d_ws, size_t ws_size,
                              hipStream_t stream) {
    const float* x      = (const float*)d_in[0];
    const float* style  = (const float*)d_in[1];
    const float* weight = (const float*)d_in[2];
    float* out = (float*)d_out;

    const size_t wmod_bytes = (size_t)BATCH * 9 * OUTC * CIN * sizeof(unsigned short);
    if (ws_size >= wmod_bytes) {
        int total = BATCH * 9 * OUTC * CIN;
        wmod_kernel<<<(total + 255) / 256, 256, 0, stream>>>(weight, style,
                                                             (unsigned short*)d_ws);
        conv_kernel<true><<<dim3(256, BATCH), 256, 0, stream>>>(
            x, (const unsigned short*)d_ws, nullptr, nullptr, out);
    } else {
        conv_kernel<false><<<dim3(256, BATCH), 256, 0, stream>>>(
            x, nullptr, weight, style, out);
    }
}

// Round 6
// 258.587 us; speedup vs baseline: 1.1862x; 1.1814x over previous
//
#include <hip/hip_runtime.h>
#include <hip/hip_bf16.h>

#define BATCH 8
#define CIN   128
#define HH    256
#define WW    256
#define OUTC  64
#define INCH  1152   // CIN*9
#define HW    (HH*WW)

typedef __attribute__((ext_vector_type(8))) short short8;
typedef __attribute__((ext_vector_type(4))) float f32x4;

__device__ __forceinline__ unsigned short bf16r(float f) {
    unsigned u = __builtin_bit_cast(unsigned, f);
    u += 0x7fffu + ((u >> 16) & 1u);
    return (unsigned short)(u >> 16);
}

// wmod[b][tap][o][c] = bf16(weight[o][c*9+tap] * style[b][c*9+tap])
__global__ void __launch_bounds__(256) wmod_kernel(const float* __restrict__ weight,
                                                   const float* __restrict__ style,
                                                   unsigned short* __restrict__ wmod) {
    int i = blockIdx.x * 256 + threadIdx.x;
    if (i >= BATCH * 9 * OUTC * CIN) return;
    int c    = i & (CIN - 1);
    int rest = i >> 7;
    int o    = rest & (OUTC - 1);
    int bt   = rest >> 6;          // b*9 + tap
    int tap  = bt % 9;
    int b    = bt / 9;
    int k    = c * 9 + tap;
    float v = weight[o * INCH + k] * style[b * INCH + k];
    wmod[i] = bf16r(v);
}

// Block: 64 outputs x (8 rows x 32 cols) pixels. 4 waves, each 64 o x 64 px.
// Chunk = 32 channels (one MFMA K). LDS: paired pixel-rows, 128B/q-row:
//   addr(s,c) = (s>>1)*64 + (((((s&1)<<2)|(c>>3)) ^ ((s>>2)&7))*8 + (c&7)
// h(q)=(q>>1)&7 is injective on stride-2 q windows -> staging ds_write_b128
// conflict-free; read path is conflict-free for any h (each q-row gets all
// 8 granules from 4 kg x 2 parity lanes).
// Staging: macro-task = 8 channels x 4 aligned pixels: 8x float4 global loads
// (16B per outstanding load -> 4x bytes-in-flight vs dword gather) + 4x
// ds_write_b128. Halo columns (col 0, 33) via 80 scalar 8-dword gather tasks.
template <bool GW>
__global__ void __launch_bounds__(256, 4) conv_kernel(
    const float* __restrict__ x,
    const unsigned short* __restrict__ wmod,
    const float* __restrict__ weight,
    const float* __restrict__ style,
    float* __restrict__ out)
{
    __shared__ __align__(16) unsigned short xs_sm[170 * 64];

    const int tid = threadIdx.x;
    const int bx  = blockIdx.x;            // 0..255 spatial tile
    const int b   = blockIdx.y;            // batch
    const int h0  = (bx >> 3) * 8;
    const int w0  = (bx & 7) * 32;

    const int wv  = tid >> 6;
    const int l15 = tid & 15;
    const int kg  = (tid >> 4) & 3;

    int sbase[4];
#pragma unroll
    for (int ni = 0; ni < 4; ++ni) {
        int p = wv * 64 + ni * 16 + l15;
        sbase[ni] = (p >> 5) * 34 + (p & 31);
    }

    f32x4 acc[4][4];
#pragma unroll
    for (int mi = 0; mi < 4; ++mi)
#pragma unroll
        for (int ni = 0; ni < 4; ++ni) acc[mi][ni] = (f32x4){0.f, 0.f, 0.f, 0.f};

    for (int chunk = 0; chunk < 4; ++chunk) {
        if (chunk) __syncthreads();        // protect xs from previous readers

        const float* xb = x + ((size_t)(b * CIN + chunk * 32)) * HW;

        // ---- main staging: 320 macro tasks (cg 0..3, r 0..9, qw 0..7)
        for (int mt = tid; mt < 320; mt += 256) {
            int cg = mt / 80;
            int rq = mt - cg * 80;
            int r  = rq >> 3;
            int qw = rq & 7;
            int h  = h0 - 1 + r;
            bool ok = (unsigned)h < HH;
            const float* xp = xb + (size_t)(cg * 8) * HW + h * WW + (w0 + qw * 4);
            f32x4 f[8];
#pragma unroll
            for (int j = 0; j < 8; ++j)
                f[j] = ok ? *(const f32x4*)(xp + (size_t)j * HW)
                          : (f32x4){0.f, 0.f, 0.f, 0.f};
#pragma unroll
            for (int u = 0; u < 4; ++u) {
                short8 sv;
#pragma unroll
                for (int j = 0; j < 8; ++j) sv[j] = (short)bf16r(f[j][u]);
                int s = r * 34 + 1 + qw * 4 + u;
                int g = (((s & 1) << 2) | cg) ^ ((s >> 2) & 7);
                *(short8*)&xs_sm[(s >> 1) * 64 + g * 8] = sv;
            }
        }

        // ---- halo columns (col 0 and 33): 80 gather tasks
        if (tid < 80) {
            int e   = tid / 40;            // 0: col 0, 1: col 33
            int rc  = tid - e * 40;
            int cg  = rc / 10;
            int r   = rc - cg * 10;
            int col = e * 33;
            int h = h0 - 1 + r, w = w0 - 1 + col;
            bool ok = ((unsigned)h < HH) && ((unsigned)w < WW);
            const float* xp = xb + (size_t)(cg * 8) * HW + h * WW + w;
            short8 sv;
#pragma unroll
            for (int j = 0; j < 8; ++j)
                sv[j] = (short)bf16r(ok ? xp[(size_t)j * HW] : 0.f);
            int s = r * 34 + col;
            int g = (((s & 1) << 2) | cg) ^ ((s >> 2) & 7);
            *(short8*)&xs_sm[(s >> 1) * 64 + g * 8] = sv;
        }
        __syncthreads();

        // ---- 9 taps: A from wmod (L2-hot) into regs, B from swizzled LDS
        const unsigned short* wmb = wmod + ((size_t)(b * 9) * OUTC) * CIN + chunk * 32;
#pragma unroll
        for (int tap = 0; tap < 9; ++tap) {
            const int kh = tap / 3, kw = tap % 3;

            short8 A[4];
            if (GW) {
                const unsigned short* wt = wmb + (size_t)tap * OUTC * CIN;
#pragma unroll
                for (int mi = 0; mi < 4; ++mi)
                    A[mi] = *(const short8*)(wt + (mi * 16 + l15) * CIN + kg * 8);
            } else {
#pragma unroll
                for (int mi = 0; mi < 4; ++mi) {
                    int o = mi * 16 + l15;
#pragma unroll
                    for (int j = 0; j < 8; ++j) {
                        int c = chunk * 32 + kg * 8 + j;
                        int k = c * 9 + tap;
                        A[mi][j] = (short)bf16r(weight[o * INCH + k] *
                                                style[b * INCH + k]);
                    }
                }
            }

            short8 Bv[4];
#pragma unroll
            for (int ni = 0; ni < 4; ++ni) {
                int s = sbase[ni] + kh * 34 + kw;
                int g = (((s & 1) << 2) | kg) ^ ((s >> 2) & 7);
                Bv[ni] = *(const short8*)&xs_sm[(s >> 1) * 64 + g * 8];
            }
#pragma unroll
            for (int mi = 0; mi < 4; ++mi)
#pragma unroll
                for (int ni = 0; ni < 4; ++ni)
                    acc[mi][ni] = __builtin_amdgcn_mfma_f32_16x16x32_bf16(
                        A[mi], Bv[ni], acc[mi][ni], 0, 0, 0);
        }
    }

    // ---- epilogue: D mapping col=lane&15 (pixel), row=(lane>>4)*4+r (o)
    float* op = out + ((size_t)b * OUTC) * HW;
#pragma unroll
    for (int mi = 0; mi < 4; ++mi) {
#pragma unroll
        for (int ni = 0; ni < 4; ++ni) {
            int p = wv * 64 + ni * 16 + l15;
            int h = h0 + (p >> 5), w = w0 + (p & 31);
#pragma unroll
            for (int r = 0; r < 4; ++r) {
                int o = mi * 16 + kg * 4 + r;
                op[(size_t)o * HW + h * WW + w] = acc[mi][ni][r];
            }
        }
    }
}

extern "C" void kernel_launch(void* const* d_in, const int* in_sizes, int n_in,
                              void* d_out, int out_size, void* d_ws, size_t ws_size,
                              hipStream_t stream) {
    const float* x      = (const float*)d_in[0];
    const float* style  = (const float*)d_in[1];
    const float* weight = (const float*)d_in[2];
    float* out = (float*)d_out;

    const size_t wmod_bytes = (size_t)BATCH * 9 * OUTC * CIN * sizeof(unsigned short);
    if (ws_size >= wmod_bytes) {
        int total = BATCH * 9 * OUTC * CIN;
        wmod_kernel<<<(total + 255) / 256, 256, 0, stream>>>(weight, style,
                                                             (unsigned short*)d_ws);
        conv_kernel<true><<<dim3(256, BATCH), 256, 0, stream>>>(
            x, (const unsigned short*)d_ws, nullptr, nullptr, out);
    } else {
        conv_kernel<false><<<dim3(256, BATCH), 256, 0, stream>>>(
            x, nullptr, weight, style, out);
    }
}

// Round 7
// 227.404 us; speedup vs baseline: 1.3489x; 1.1371x over previous
//
#include <hip/hip_runtime.h>
#include <hip/hip_bf16.h>

#define BATCH 8
#define CIN   128
#define HH    256
#define WW    256
#define OUTC  64
#define INCH  1152   // CIN*9
#define HW    (HH*WW)

typedef __attribute__((ext_vector_type(8))) short short8;
typedef __attribute__((ext_vector_type(4))) float f32x4;

__device__ __forceinline__ unsigned short bf16r(float f) {
    unsigned u = __builtin_bit_cast(unsigned, f);
    u += 0x7fffu + ((u >> 16) & 1u);
    return (unsigned short)(u >> 16);
}

// wmod[b][tap][o][c] = bf16(weight[o][c*9+tap] * style[b][c*9+tap])
__global__ void __launch_bounds__(256) wmod_kernel(const float* __restrict__ weight,
                                                   const float* __restrict__ style,
                                                   unsigned short* __restrict__ wmod) {
    int i = blockIdx.x * 256 + threadIdx.x;
    if (i >= BATCH * 9 * OUTC * CIN) return;
    int c    = i & (CIN - 1);
    int rest = i >> 7;
    int o    = rest & (OUTC - 1);
    int bt   = rest >> 6;          // b*9 + tap
    int tap  = bt % 9;
    int b    = bt / 9;
    int k    = c * 9 + tap;
    float v = weight[o * INCH + k] * style[b * INCH + k];
    wmod[i] = bf16r(v);
}

// Block: 512 threads = 8 waves. Output tile 64o x (8h x 32w) px.
// Wave (wr = wv>>2, wc = wv&3): 32o x 64px -> acc[2][4] = 32 f32/lane
// (halved vs 4-wave version -> ~84 total regs -> 6 waves/SIMD, 24 waves/CU).
// Chunk = 32 channels. LDS: paired pixel-rows, 128B/q-row:
//   addr(s,c) = (s>>1)*64 + (((((s&1)<<2)|(c>>3)) ^ ((s>>1)&7))*8 + (c&7)
// (q&7 hash: measured 3.5x fewer conflicts than (s>>2)&7).
// Staging: 400 tasks (cg 0..3, r 0..9, wq 0..9), each 8 channels x one
// 16B-aligned float4 quad covering w0-4..w0+35 -> halo included, no scalar
// gathers; OOB handled by clamp+mask (zeros written for pad pixels).
template <bool GW>
__global__ void __launch_bounds__(512, 4) conv_kernel(
    const float* __restrict__ x,
    const unsigned short* __restrict__ wmod,
    const float* __restrict__ weight,
    const float* __restrict__ style,
    float* __restrict__ out)
{
    __shared__ __align__(16) unsigned short xs_sm[170 * 64];

    const int tid = threadIdx.x;           // 0..511
    const int bx  = blockIdx.x;            // 0..255 spatial tile
    const int b   = blockIdx.y;            // batch
    const int h0  = (bx >> 3) * 8;
    const int w0  = (bx & 7) * 32;

    const int wv  = tid >> 6;              // 0..7
    const int wr  = wv >> 2;               // o-half
    const int wc  = wv & 3;                // px-quarter
    const int l15 = tid & 15;
    const int kg  = (tid >> 4) & 3;

    int sbase[4];
#pragma unroll
    for (int ni = 0; ni < 4; ++ni) {
        int p = wc * 64 + ni * 16 + l15;
        sbase[ni] = (p >> 5) * 34 + (p & 31);
    }

    // ---- staging task geometry (one task per thread, tid < 400)
    const bool tvalid = tid < 400;
    const int scg = tvalid ? tid / 100 : 0;
    const int srw = tvalid ? tid % 100 : 0;
    const int sr  = srw / 10;
    const int swq = srw % 10;
    const int sh  = h0 - 1 + sr;
    const bool hok = (unsigned)sh < HH;
    const int wload  = w0 - 4 + swq * 4;
    const int wclamp = min(max(wload, 0), WW - 4);
    const int gbase  = (hok ? sh : 0) * WW + wclamp;

    f32x4 acc[2][4];
#pragma unroll
    for (int mi = 0; mi < 2; ++mi)
#pragma unroll
        for (int ni = 0; ni < 4; ++ni) acc[mi][ni] = (f32x4){0.f, 0.f, 0.f, 0.f};

    for (int chunk = 0; chunk < 4; ++chunk) {
        if (chunk) __syncthreads();        // protect xs from previous readers

        // ---- stage 32 channels: 8x float4 per task + up to 4 ds_write_b128
        if (tvalid) {
            const float* xp =
                x + ((size_t)(b * CIN + chunk * 32 + scg * 8)) * HW + gbase;
            f32x4 f[8];
#pragma unroll
            for (int j = 0; j < 8; ++j)
                f[j] = hok ? *(const f32x4*)(xp + (size_t)j * HW)
                           : (f32x4){0.f, 0.f, 0.f, 0.f};
#pragma unroll
            for (int u = 0; u < 4; ++u) {
                int w   = wload + u;
                int col = w - (w0 - 1);
                if (col >= 0 && col <= 33) {
                    bool wok = hok && ((unsigned)w < WW);
                    short8 sv;
#pragma unroll
                    for (int j = 0; j < 8; ++j)
                        sv[j] = wok ? (short)bf16r(f[j][u]) : (short)0;
                    int s = sr * 34 + col;
                    int q = s >> 1;
                    int g = (((s & 1) << 2) | scg) ^ (q & 7);
                    *(short8*)&xs_sm[q * 64 + g * 8] = sv;
                }
            }
        }
        __syncthreads();

        // ---- 9 taps: A from wmod (L2-hot) into regs, B from swizzled LDS
        const unsigned short* wmb = wmod + ((size_t)(b * 9) * OUTC) * CIN + chunk * 32;
#pragma unroll
        for (int tap = 0; tap < 9; ++tap) {
            const int kh = tap / 3, kw = tap % 3;

            short8 A[2];
            if (GW) {
                const unsigned short* wt = wmb + (size_t)tap * OUTC * CIN;
#pragma unroll
                for (int mi = 0; mi < 2; ++mi)
                    A[mi] = *(const short8*)(wt + (wr * 32 + mi * 16 + l15) * CIN +
                                             kg * 8);
            } else {
#pragma unroll
                for (int mi = 0; mi < 2; ++mi) {
                    int o = wr * 32 + mi * 16 + l15;
#pragma unroll
                    for (int j = 0; j < 8; ++j) {
                        int c = chunk * 32 + kg * 8 + j;
                        int k = c * 9 + tap;
                        A[mi][j] = (short)bf16r(weight[o * INCH + k] *
                                                style[b * INCH + k]);
                    }
                }
            }

            short8 Bv[4];
#pragma unroll
            for (int ni = 0; ni < 4; ++ni) {
                int s = sbase[ni] + kh * 34 + kw;
                int q = s >> 1;
                int g = (((s & 1) << 2) | kg) ^ (q & 7);
                Bv[ni] = *(const short8*)&xs_sm[q * 64 + g * 8];
            }
#pragma unroll
            for (int mi = 0; mi < 2; ++mi)
#pragma unroll
                for (int ni = 0; ni < 4; ++ni)
                    acc[mi][ni] = __builtin_amdgcn_mfma_f32_16x16x32_bf16(
                        A[mi], Bv[ni], acc[mi][ni], 0, 0, 0);
        }
    }

    // ---- epilogue: D mapping col=lane&15 (pixel), row=(lane>>4)*4+r (o)
    float* op = out + ((size_t)b * OUTC) * HW;
#pragma unroll
    for (int mi = 0; mi < 2; ++mi) {
#pragma unroll
        for (int ni = 0; ni < 4; ++ni) {
            int p = wc * 64 + ni * 16 + l15;
            int h = h0 + (p >> 5), w = w0 + (p & 31);
#pragma unroll
            for (int r = 0; r < 4; ++r) {
                int o = wr * 32 + mi * 16 + kg * 4 + r;
                op[(size_t)o * HW + h * WW + w] = acc[mi][ni][r];
            }
        }
    }
}

extern "C" void kernel_launch(void* const* d_in, const int* in_sizes, int n_in,
                              void* d_out, int out_size, void* d_ws, size_t ws_size,
                              hipStream_t stream) {
    const float* x      = (const float*)d_in[0];
    const float* style  = (const float*)d_in[1];
    const float* weight = (const float*)d_in[2];
    float* out = (float*)d_out;

    const size_t wmod_bytes = (size_t)BATCH * 9 * OUTC * CIN * sizeof(unsigned short);
    if (ws_size >= wmod_bytes) {
        int total = BATCH * 9 * OUTC * CIN;
        wmod_kernel<<<(total + 255) / 256, 256, 0, stream>>>(weight, style,
                                                             (unsigned short*)d_ws);
        conv_kernel<true><<<dim3(256, BATCH), 512, 0, stream>>>(
            x, (const unsigned short*)d_ws, nullptr, nullptr, out);
    } else {
        conv_kernel<false><<<dim3(256, BATCH), 512, 0, stream>>>(
            x, nullptr, weight, style, out);
    }
}